// Round 1
// baseline (12.130 us; speedup 1.0000x reference)
//
#include <hip/hip_runtime.h>

// Problem constants (match reference file)
#define S_SAMPLES 1000
#define DIM 512   // floats per row = 128 float4s

// Pass 1: one 64-lane wave per sample s.
// Lane l loads float4 #l and #(l+64) of rows i,j,k (coalesced, 128 float4/row),
// accumulates dot(ei,ej), dot(ej,ek), dot(ei,ek) and the three self-dots,
// butterfly-reduces across the wave, and lane 0 writes the per-sample
// violation into ws[s].
__global__ __launch_bounds__(256) void trans_pass1(
    const float* __restrict__ emb,
    const int* __restrict__ i_idx,
    const int* __restrict__ j_idx,
    const int* __restrict__ k_idx,
    float* __restrict__ viol)
{
    const int gtid = blockIdx.x * blockDim.x + threadIdx.x;
    const int s    = gtid >> 6;          // wave id = sample id
    const int lane = threadIdx.x & 63;
    if (s >= S_SAMPLES) return;

    const long long ri = (long long)i_idx[s] * DIM;
    const long long rj = (long long)j_idx[s] * DIM;
    const long long rk = (long long)k_idx[s] * DIM;
    const float4* pi = (const float4*)(emb + ri);
    const float4* pj = (const float4*)(emb + rj);
    const float4* pk = (const float4*)(emb + rk);

    float dij = 0.f, djk = 0.f, dik = 0.f;
    float nii = 0.f, njj = 0.f, nkk = 0.f;

#pragma unroll
    for (int t = 0; t < 2; ++t) {
        const int o = lane + 64 * t;     // 0..127 float4 index within the row
        float4 a = pi[o];
        float4 b = pj[o];
        float4 c = pk[o];
        dij += a.x*b.x + a.y*b.y + a.z*b.z + a.w*b.w;
        djk += b.x*c.x + b.y*c.y + b.z*c.z + b.w*c.w;
        dik += a.x*c.x + a.y*c.y + a.z*c.z + a.w*c.w;
        nii += a.x*a.x + a.y*a.y + a.z*a.z + a.w*a.w;
        njj += b.x*b.x + b.y*b.y + b.z*b.z + b.w*b.w;
        nkk += c.x*c.x + c.y*c.y + c.z*c.z + c.w*c.w;
    }

    // 64-lane butterfly reduction (deterministic)
#pragma unroll
    for (int off = 32; off > 0; off >>= 1) {
        dij += __shfl_xor(dij, off);
        djk += __shfl_xor(djk, off);
        dik += __shfl_xor(dik, off);
        nii += __shfl_xor(nii, off);
        njj += __shfl_xor(njj, off);
        nkk += __shfl_xor(nkk, off);
    }

    if (lane == 0) {
        const float EPS = 1e-12f;
        const float ni = fmaxf(sqrtf(nii), EPS);
        const float nj = fmaxf(sqrtf(njj), EPS);
        const float nk = fmaxf(sqrtf(nkk), EPS);
        const float sij = dij / (ni * nj);
        const float sjk = djk / (nj * nk);
        const float sik = dik / (ni * nk);
        // TEMPERATURE == 1.0
        const float pij = 1.f / (1.f + expf(-sij));
        const float pjk = 1.f / (1.f + expf(-sjk));
        const float pik = 1.f / (1.f + expf(-sik));
        viol[s] = fmaxf(pij * pjk - pik, 0.f);
    }
}

// Pass 2: single block, deterministic tree reduction of the 1000 violations.
__global__ __launch_bounds__(256) void trans_pass2(
    const float* __restrict__ viol,
    float* __restrict__ out)
{
    __shared__ float wsum[4];
    const int t = threadIdx.x;
    float s = 0.f;
    for (int idx = t; idx < S_SAMPLES; idx += 256) s += viol[idx];
#pragma unroll
    for (int off = 32; off > 0; off >>= 1) s += __shfl_xor(s, off);
    if ((t & 63) == 0) wsum[t >> 6] = s;
    __syncthreads();
    if (t == 0) {
        const float tot = wsum[0] + wsum[1] + wsum[2] + wsum[3];
        out[0] = tot * (1.0f / (float)S_SAMPLES);
    }
}

extern "C" void kernel_launch(void* const* d_in, const int* in_sizes, int n_in,
                              void* d_out, int out_size, void* d_ws, size_t ws_size,
                              hipStream_t stream) {
    const float* emb  = (const float*)d_in[0];
    const int* i_idx  = (const int*)d_in[1];
    const int* j_idx  = (const int*)d_in[2];
    const int* k_idx  = (const int*)d_in[3];
    float* out  = (float*)d_out;
    float* viol = (float*)d_ws;   // S_SAMPLES floats of scratch

    // 1000 waves, 4 waves (256 threads) per block -> 250 blocks
    const int blocks = (S_SAMPLES * 64 + 255) / 256;
    trans_pass1<<<blocks, 256, 0, stream>>>(emb, i_idx, j_idx, k_idx, viol);
    trans_pass2<<<1, 256, 0, stream>>>(viol, out);
}